// Round 1
// baseline (318.274 us; speedup 1.0000x reference)
//
#include <hip/hip_runtime.h>
#include <hip/hip_bf16.h>

// Problem constants
#define BATCH   32
#define CIN     256
#define COUT    64
#define HW      1024          // 32*32
#define NE      1024          // codebook size
#define ED      64            // code dim
#define NROW    32768         // BATCH*COUT*HW/ED
#define ZTOT    2097152       // BATCH*COUT*HW

// d_out layout (floats): z_q_st[ZTOT], loss[1], sampled[32768], min_idx[32768]
#define OFF_LOSS 2097152
#define OFF_SAMP 2097153
#define OFF_IDX  2129921

// LDS strides (floats), multiples of 4 for aligned float4
#define XSTR 68
#define ESTR 132

// ---------------------------------------------------------------------------
// k_init: blocks 0..127 zero the sampled region (+ sse accumulator);
//         blocks 128..131 compute codebook row norms (numpy-pairwise).
__global__ __launch_bounds__(256) void k_init(float* __restrict__ out_samp,
                                              double* __restrict__ sse,
                                              const float* __restrict__ emb,
                                              float* __restrict__ enorm,
                                              float* __restrict__ invn) {
    int b = blockIdx.x;
    if (b < 128) {
        int i = b * 256 + threadIdx.x;     // 0..32767
        out_samp[i] = 0.0f;
        if (b == 0 && threadIdx.x == 0) *sse = 0.0;
    } else {
        int j = (b - 128) * 256 + threadIdx.x;   // 0..1023
        const float* e = emb + j * ED;
        // numpy pairwise sum: 8 strided accumulators + fixed combine order
        float r8[8];
        #pragma unroll
        for (int s = 0; s < 8; s++) { float x = e[s]; r8[s] = x * x; }
        #pragma unroll
        for (int m = 1; m < 8; m++) {
            #pragma unroll
            for (int s = 0; s < 8; s++) { float x = e[8 * m + s]; r8[s] += x * x; }
        }
        float en = ((r8[0] + r8[1]) + (r8[2] + r8[3])) + ((r8[4] + r8[5]) + (r8[6] + r8[7]));
        enorm[j] = en;
        invn[j]  = 1.0f / sqrtf(en);
    }
}

// ---------------------------------------------------------------------------
// k_contrast: mean pairwise cosine = ||sum_i e_i/||e_i||||^2 / NE^2
__global__ __launch_bounds__(256) void k_contrast(const float* __restrict__ emb,
                                                  const float* __restrict__ invn,
                                                  float* __restrict__ contrast) {
    int t = threadIdx.x;
    int d = t & 63, q = t >> 6;
    float s = 0.0f;
    for (int i = q; i < NE; i += 4)
        s = fmaf(emb[i * ED + d], invn[i], s);
    __shared__ float S[256];
    S[t] = s;
    __syncthreads();
    if (t < 64) {
        float v = (S[t] + S[t + 64]) + (S[t + 128] + S[t + 192]);
        float sq = v * v;
        #pragma unroll
        for (int off = 32; off > 0; off >>= 1) sq += __shfl_down(sq, off, 64);
        if (t == 0) *contrast = sq / (1024.0f * 1024.0f);
    }
}

// ---------------------------------------------------------------------------
// k_conv: z[b,o,p] = sum_c W[o,c] * x[b,c,p] + bias[o]
// Per block: one batch b, 64-pixel tile. Micro-tile 4px x 4out per thread.
// LDS layouts: Xs[c][px] (stride XSTR), Ws[c][o] (stride XSTR) -> conflict-free
// float4 reads along px / o. K accumulation strictly sequential (c=0..255, fma).
__global__ __launch_bounds__(256) void k_conv(const float* __restrict__ x,
                                              const float* __restrict__ w,
                                              const float* __restrict__ bias,
                                              float* __restrict__ z) {
    __shared__ float Xs[64 * XSTR];
    __shared__ float Ws[64 * XSTR];
    int t  = threadIdx.x;
    int b  = blockIdx.y;
    int p0 = blockIdx.x * 64;
    int pg = t & 15;        // px group: px = 4*pg + i
    int og = t >> 4;        // o  group: o  = 4*og + j
    float acc[4][4];
    #pragma unroll
    for (int i = 0; i < 4; i++)
        #pragma unroll
        for (int j = 0; j < 4; j++) acc[i][j] = 0.0f;

    for (int c0 = 0; c0 < CIN; c0 += 64) {
        __syncthreads();
        {
            int u = t & 15, cg2 = t >> 4;
            #pragma unroll
            for (int m = 0; m < 4; m++) {
                int c = cg2 + 16 * m;
                float4 v = *(const float4*)&x[(size_t)(b * CIN + c0 + c) * HW + p0 + 4 * u];
                *(float4*)&Xs[c * XSTR + 4 * u] = v;
            }
            #pragma unroll
            for (int m = 0; m < 4; m++) {
                int o = cg2 + 16 * m;
                float4 v = *(const float4*)&w[o * CIN + c0 + 4 * u];
                Ws[(4 * u + 0) * XSTR + o] = v.x;
                Ws[(4 * u + 1) * XSTR + o] = v.y;
                Ws[(4 * u + 2) * XSTR + o] = v.z;
                Ws[(4 * u + 3) * XSTR + o] = v.w;
            }
        }
        __syncthreads();
        #pragma unroll 8
        for (int k = 0; k < 64; k++) {
            float4 xv = *(const float4*)&Xs[k * XSTR + 4 * pg];
            float4 wv = *(const float4*)&Ws[k * XSTR + 4 * og];
            float xa[4] = {xv.x, xv.y, xv.z, xv.w};
            float wb[4] = {wv.x, wv.y, wv.z, wv.w};
            #pragma unroll
            for (int i = 0; i < 4; i++)
                #pragma unroll
                for (int j = 0; j < 4; j++)
                    acc[i][j] = fmaf(xa[i], wb[j], acc[i][j]);
        }
    }
    #pragma unroll
    for (int j = 0; j < 4; j++) {
        int o = 4 * og + j;
        float bv = bias[o];
        float4 out;
        out.x = acc[0][j] + bv;
        out.y = acc[1][j] + bv;
        out.z = acc[2][j] + bv;
        out.w = acc[3][j] + bv;
        *(float4*)&z[(size_t)(b * COUT + o) * HW + p0 + 4 * pg] = out;
    }
}

// ---------------------------------------------------------------------------
// k_dist: for 64 rows/block, distances to all 1024 codes, argmin (first-min).
// LDS transposed layouts zs[k][row], es[k][code] -> conflict-free f4 reads.
// Micro-tile 4 rows x 8 codes; per k: 3 b128 reads + 32 fma.
__global__ __launch_bounds__(256) void k_dist(const float* __restrict__ z,
                                              const float* __restrict__ emb,
                                              const float* __restrict__ enorm,
                                              int* __restrict__ widx,
                                              float* __restrict__ out_idx,
                                              float* __restrict__ out_samp) {
    __shared__ float zs[64 * XSTR];      // [k][row]
    __shared__ float es[64 * ESTR];      // [k][code_local]
    __shared__ float zn_s[64];
    __shared__ float en_s[128];
    __shared__ float redd_s[16 * 64];
    __shared__ int   redj_s[16 * 64];
    int t = threadIdx.x;
    int row0 = blockIdx.x * 64;
    int rg = t & 15;     // rows  4*rg + i
    int cg = t >> 4;     // codes 8*cg + j (local)

    // stage zs transposed: zs[k][r]
    {
        int k = t & 63, wv = t >> 6;
        #pragma unroll
        for (int m = 0; m < 4; m++) {
            int v = wv + 4 * m;          // 0..15
            float4 val;
            val.x = z[(size_t)(row0 + 4 * v + 0) * ED + k];
            val.y = z[(size_t)(row0 + 4 * v + 1) * ED + k];
            val.z = z[(size_t)(row0 + 4 * v + 2) * ED + k];
            val.w = z[(size_t)(row0 + 4 * v + 3) * ED + k];
            *(float4*)&zs[k * XSTR + 4 * v] = val;
        }
    }
    // zn: numpy-pairwise sum of squares per row (exact grid-shift argument
    // makes method choice non-critical, but mirror numpy anyway)
    if (t < 64) {
        const float* zr = z + (size_t)(row0 + t) * ED;
        float r8[8];
        #pragma unroll
        for (int s = 0; s < 8; s++) { float xx = zr[s]; r8[s] = xx * xx; }
        #pragma unroll
        for (int m = 1; m < 8; m++) {
            #pragma unroll
            for (int s = 0; s < 8; s++) { float xx = zr[8 * m + s]; r8[s] += xx * xx; }
        }
        zn_s[t] = ((r8[0] + r8[1]) + (r8[2] + r8[3])) + ((r8[4] + r8[5]) + (r8[6] + r8[7]));
    }

    float bestd[4];
    int   bestj[4];
    #pragma unroll
    for (int i = 0; i < 4; i++) { bestd[i] = __builtin_huge_valf(); bestj[i] = 0; }

    for (int ch = 0; ch < 8; ch++) {
        int c0 = ch * 128;
        __syncthreads();   // protect es/en_s from prior-iteration readers
        {
            int k = t & 63, wv = t >> 6;
            #pragma unroll
            for (int m = 0; m < 8; m++) {
                int v = wv + 4 * m;      // 0..31
                float4 val;
                val.x = emb[(size_t)(c0 + 4 * v + 0) * ED + k];
                val.y = emb[(size_t)(c0 + 4 * v + 1) * ED + k];
                val.z = emb[(size_t)(c0 + 4 * v + 2) * ED + k];
                val.w = emb[(size_t)(c0 + 4 * v + 3) * ED + k];
                *(float4*)&es[k * ESTR + 4 * v] = val;
            }
            if (t < 32) {
                float4 ev4 = *(const float4*)&enorm[c0 + 4 * t];
                *(float4*)&en_s[4 * t] = ev4;
            }
        }
        __syncthreads();

        float acc[4][8];
        #pragma unroll
        for (int i = 0; i < 4; i++)
            #pragma unroll
            for (int j = 0; j < 8; j++) acc[i][j] = 0.0f;

        #pragma unroll 8
        for (int k = 0; k < 64; k++) {
            float4 xv = *(const float4*)&zs[k * XSTR + 4 * rg];
            float4 e0 = *(const float4*)&es[k * ESTR + 8 * cg];
            float4 e1 = *(const float4*)&es[k * ESTR + 8 * cg + 4];
            float xa[4] = {xv.x, xv.y, xv.z, xv.w};
            float eb[8] = {e0.x, e0.y, e0.z, e0.w, e1.x, e1.y, e1.z, e1.w};
            #pragma unroll
            for (int i = 0; i < 4; i++)
                #pragma unroll
                for (int j = 0; j < 8; j++)
                    acc[i][j] = fmaf(xa[i], eb[j], acc[i][j]);
        }

        // epilogue: d = fl(fl(zn + en) - 2*dot); strict < keeps first index
        #pragma unroll
        for (int i = 0; i < 4; i++) {
            float zn = zn_s[4 * rg + i];
            #pragma unroll
            for (int j = 0; j < 8; j++) {
                int cl = 8 * cg + j;
                float A = zn + en_s[cl];
                float D = A - 2.0f * acc[i][j];
                if (D < bestd[i]) { bestd[i] = D; bestj[i] = c0 + cl; }
            }
        }
    }

    #pragma unroll
    for (int i = 0; i < 4; i++) {
        redd_s[cg * 64 + 4 * rg + i] = bestd[i];
        redj_s[cg * 64 + 4 * rg + i] = bestj[i];
    }
    __syncthreads();
    if (t < 64) {
        float bd = __builtin_huge_valf();
        int   bj = 0x7fffffff;
        #pragma unroll
        for (int c = 0; c < 16; c++) {
            float dd = redd_s[c * 64 + t];
            int   jj = redj_s[c * 64 + t];
            if (dd < bd || (dd == bd && jj < bj)) { bd = dd; bj = jj; }
        }
        int rowg = row0 + t;
        widx[rowg]    = bj;
        out_idx[rowg] = (float)bj;              // min_idx as float
        atomicExch(&out_samp[bj], 1.0f);        // device-scope, coherent
    }
}

// ---------------------------------------------------------------------------
// k_epi: z_q_st = z + (emb[idx] - z); accumulate sum((zq-z)^2)
__global__ __launch_bounds__(256) void k_epi(const float* __restrict__ z,
                                             const float* __restrict__ emb,
                                             const int* __restrict__ widx,
                                             float* __restrict__ out_zq,
                                             double* __restrict__ sse) {
    int e = blockIdx.x * 256 + threadIdx.x;
    int row = e >> 6, k = e & 63;
    int id = widx[row];
    float zv = z[e];
    float ev = emb[(id << 6) + k];
    float d  = ev - zv;
    out_zq[e] = zv + d;                 // matches z + sg(z_q - z) rounding
    float sq = d * d;
    #pragma unroll
    for (int off = 32; off > 0; off >>= 1) sq += __shfl_down(sq, off, 64);
    __shared__ float warr[4];
    int lane = threadIdx.x & 63, wv = threadIdx.x >> 6;
    if (lane == 0) warr[wv] = sq;
    __syncthreads();
    if (threadIdx.x == 0) {
        float bsum = (warr[0] + warr[1]) + (warr[2] + warr[3]);
        atomicAdd(sse, (double)bsum);
    }
}

// ---------------------------------------------------------------------------
__global__ void k_final(const double* __restrict__ sse,
                        const float* __restrict__ contrast,
                        float* __restrict__ out_loss) {
    float m = (float)(*sse / (double)ZTOT);
    float loss = m + 0.25f * m;         // LEGACY: mse + BETA*mse
    out_loss[0] = loss + *contrast;
}

// ---------------------------------------------------------------------------
extern "C" void kernel_launch(void* const* d_in, const int* in_sizes, int n_in,
                              void* d_out, int out_size, void* d_ws, size_t ws_size,
                              hipStream_t stream) {
    (void)in_sizes; (void)n_in; (void)out_size; (void)ws_size;
    const float* z_     = (const float*)d_in[0];
    const float* conv_w = (const float*)d_in[1];
    const float* conv_b = (const float*)d_in[2];
    const float* emb    = (const float*)d_in[3];

    float* out      = (float*)d_out;
    float* out_zq   = out;
    float* out_loss = out + OFF_LOSS;
    float* out_samp = out + OFF_SAMP;
    float* out_idx  = out + OFF_IDX;

    char*  ws       = (char*)d_ws;
    float* wz       = (float*)ws;                         // 2M floats
    float* enorm    = (float*)(ws + 8388608);             // 1024
    float* invn     = enorm + 1024;                       // 1024
    int*   widx     = (int*)(ws + 8396800);               // 32768
    double* sse     = (double*)(ws + 8527872);
    float* contrast = (float*)(ws + 8527880);

    k_init    <<<132, 256, 0, stream>>>(out_samp, sse, emb, enorm, invn);
    k_contrast<<<1,   256, 0, stream>>>(emb, invn, contrast);
    k_conv    <<<dim3(16, 32), 256, 0, stream>>>(z_, conv_w, conv_b, wz);
    k_dist    <<<512, 256, 0, stream>>>(wz, emb, enorm, widx, out_idx, out_samp);
    k_epi     <<<8192, 256, 0, stream>>>(wz, emb, widx, out_zq, sse);
    k_final   <<<1, 1, 0, stream>>>(sse, contrast, out_loss);
}

// Round 2
// 166.409 us; speedup vs baseline: 1.9126x; 1.9126x over previous
//
#include <hip/hip_runtime.h>
#include <hip/hip_bf16.h>

// Problem constants
#define BATCH   32
#define CIN     256
#define COUT    64
#define HW      1024          // 32*32
#define NE      1024          // codebook size
#define ED      64            // code dim
#define NROW    32768         // BATCH*COUT*HW/ED
#define ZTOT    2097152       // BATCH*COUT*HW

// d_out layout (floats): z_q_st[ZTOT], loss[1], sampled[32768], min_idx[32768]
#define OFF_LOSS 2097152
#define OFF_SAMP 2097153
#define OFF_IDX  2129921

// LDS strides (floats), multiples of 4 for aligned float4
#define XSTR 68
#define ESTR 132

// ---------------------------------------------------------------------------
// k_init: blocks 0..127 zero the sampled region; blocks 128..131 compute
// codebook row norms (numpy-pairwise) + 1/sqrt for the contrastive term.
__global__ __launch_bounds__(256) void k_init(float* __restrict__ out_samp,
                                              const float* __restrict__ emb,
                                              float* __restrict__ enorm,
                                              float* __restrict__ invn) {
    int b = blockIdx.x;
    if (b < 128) {
        int i = b * 256 + threadIdx.x;     // 0..32767
        out_samp[i] = 0.0f;
    } else {
        int j = (b - 128) * 256 + threadIdx.x;   // 0..1023
        const float* e = emb + j * ED;
        float r8[8];
        #pragma unroll
        for (int s = 0; s < 8; s++) { float x = e[s]; r8[s] = x * x; }
        #pragma unroll
        for (int m = 1; m < 8; m++) {
            #pragma unroll
            for (int s = 0; s < 8; s++) { float x = e[8 * m + s]; r8[s] += x * x; }
        }
        float en = ((r8[0] + r8[1]) + (r8[2] + r8[3])) + ((r8[4] + r8[5]) + (r8[6] + r8[7]));
        enorm[j] = en;
        invn[j]  = 1.0f / sqrtf(en);
    }
}

// ---------------------------------------------------------------------------
// k_contrast: 16 blocks; block b sums e_i/||e_i|| over its 64 codes into a
// 64-dim partial. Deterministic (fixed order within block; combine in k_final).
__global__ __launch_bounds__(256) void k_contrast(const float* __restrict__ emb,
                                                  const float* __restrict__ invn,
                                                  float* __restrict__ cpart) {
    int t = threadIdx.x;
    int b = blockIdx.x;
    int d = t & 63, q = t >> 6;
    int i0 = b * 64;
    float s = 0.0f;
    #pragma unroll
    for (int m = 0; m < 16; m++) {
        int i = i0 + q + 4 * m;
        s = fmaf(emb[i * ED + d], invn[i], s);
    }
    __shared__ float S[256];
    S[t] = s;
    __syncthreads();
    if (t < 64)
        cpart[b * 64 + t] = (S[t] + S[t + 64]) + (S[t + 128] + S[t + 192]);
}

// ---------------------------------------------------------------------------
// k_conv: z[b,o,p] = sum_c W[o,c] * x[b,c,p] + bias[o]
// Per block: one batch b, 64-pixel tile. Micro-tile 4px x 4out per thread.
// K accumulation strictly sequential (c=0..255, fma) to match BLAS rounding.
__global__ __launch_bounds__(256) void k_conv(const float* __restrict__ x,
                                              const float* __restrict__ w,
                                              const float* __restrict__ bias,
                                              float* __restrict__ z) {
    __shared__ float Xs[64 * XSTR];
    __shared__ float Ws[64 * XSTR];
    int t  = threadIdx.x;
    int b  = blockIdx.y;
    int p0 = blockIdx.x * 64;
    int pg = t & 15;        // px group: px = 4*pg + i
    int og = t >> 4;        // o  group: o  = 4*og + j
    float acc[4][4];
    #pragma unroll
    for (int i = 0; i < 4; i++)
        #pragma unroll
        for (int j = 0; j < 4; j++) acc[i][j] = 0.0f;

    for (int c0 = 0; c0 < CIN; c0 += 64) {
        __syncthreads();
        {
            int u = t & 15, cg2 = t >> 4;
            #pragma unroll
            for (int m = 0; m < 4; m++) {
                int c = cg2 + 16 * m;
                float4 v = *(const float4*)&x[(size_t)(b * CIN + c0 + c) * HW + p0 + 4 * u];
                *(float4*)&Xs[c * XSTR + 4 * u] = v;
            }
            #pragma unroll
            for (int m = 0; m < 4; m++) {
                int o = cg2 + 16 * m;
                float4 v = *(const float4*)&w[o * CIN + c0 + 4 * u];
                Ws[(4 * u + 0) * XSTR + o] = v.x;
                Ws[(4 * u + 1) * XSTR + o] = v.y;
                Ws[(4 * u + 2) * XSTR + o] = v.z;
                Ws[(4 * u + 3) * XSTR + o] = v.w;
            }
        }
        __syncthreads();
        #pragma unroll 8
        for (int k = 0; k < 64; k++) {
            float4 xv = *(const float4*)&Xs[k * XSTR + 4 * pg];
            float4 wv = *(const float4*)&Ws[k * XSTR + 4 * og];
            float xa[4] = {xv.x, xv.y, xv.z, xv.w};
            float wb[4] = {wv.x, wv.y, wv.z, wv.w};
            #pragma unroll
            for (int i = 0; i < 4; i++)
                #pragma unroll
                for (int j = 0; j < 4; j++)
                    acc[i][j] = fmaf(xa[i], wb[j], acc[i][j]);
        }
    }
    #pragma unroll
    for (int j = 0; j < 4; j++) {
        int o = 4 * og + j;
        float bv = bias[o];
        float4 out;
        out.x = acc[0][j] + bv;
        out.y = acc[1][j] + bv;
        out.z = acc[2][j] + bv;
        out.w = acc[3][j] + bv;
        *(float4*)&z[(size_t)(b * COUT + o) * HW + p0 + 4 * pg] = out;
    }
}

// ---------------------------------------------------------------------------
// k_dist: 64 rows/block, distances to all 1024 codes, argmin (first-min),
// THEN fused epilogue: gather emb[best], write z_q_st, per-block SSE partial.
// No global atomics on a single address (R1 post-mortem: 8192 same-address
// double atomics serialized at ~30 cyc each = 102 us).
__global__ __launch_bounds__(256) void k_dist(const float* __restrict__ z,
                                              const float* __restrict__ emb,
                                              const float* __restrict__ enorm,
                                              float* __restrict__ out_idx,
                                              float* __restrict__ out_samp,
                                              float* __restrict__ out_zq,
                                              float* __restrict__ ssep) {
    __shared__ float zs[64 * XSTR];      // [k][row] transposed
    __shared__ float es[64 * ESTR];      // [k][code_local]
    __shared__ float zn_s[64];
    __shared__ float en_s[128];
    __shared__ float redd_s[16 * 64];
    __shared__ int   redj_s[16 * 64];
    __shared__ int   bj_s[64];
    __shared__ float warr[4];
    int t = threadIdx.x;
    int row0 = blockIdx.x * 64;
    int rg = t & 15;     // rows  4*rg + i
    int cg = t >> 4;     // codes 8*cg + j (local)

    // stage zs transposed: zs[k][r]
    {
        int k = t & 63, wv = t >> 6;
        #pragma unroll
        for (int m = 0; m < 4; m++) {
            int v = wv + 4 * m;          // 0..15
            float4 val;
            val.x = z[(size_t)(row0 + 4 * v + 0) * ED + k];
            val.y = z[(size_t)(row0 + 4 * v + 1) * ED + k];
            val.z = z[(size_t)(row0 + 4 * v + 2) * ED + k];
            val.w = z[(size_t)(row0 + 4 * v + 3) * ED + k];
            *(float4*)&zs[k * XSTR + 4 * v] = val;
        }
    }
    // zn: numpy-pairwise sum of squares per row
    if (t < 64) {
        const float* zr = z + (size_t)(row0 + t) * ED;
        float r8[8];
        #pragma unroll
        for (int s = 0; s < 8; s++) { float xx = zr[s]; r8[s] = xx * xx; }
        #pragma unroll
        for (int m = 1; m < 8; m++) {
            #pragma unroll
            for (int s = 0; s < 8; s++) { float xx = zr[8 * m + s]; r8[s] += xx * xx; }
        }
        zn_s[t] = ((r8[0] + r8[1]) + (r8[2] + r8[3])) + ((r8[4] + r8[5]) + (r8[6] + r8[7]));
    }

    float bestd[4];
    int   bestj[4];
    #pragma unroll
    for (int i = 0; i < 4; i++) { bestd[i] = __builtin_huge_valf(); bestj[i] = 0; }

    for (int ch = 0; ch < 8; ch++) {
        int c0 = ch * 128;
        __syncthreads();   // protect es/en_s from prior-iteration readers
        {
            int k = t & 63, wv = t >> 6;
            #pragma unroll
            for (int m = 0; m < 8; m++) {
                int v = wv + 4 * m;      // 0..31
                float4 val;
                val.x = emb[(size_t)(c0 + 4 * v + 0) * ED + k];
                val.y = emb[(size_t)(c0 + 4 * v + 1) * ED + k];
                val.z = emb[(size_t)(c0 + 4 * v + 2) * ED + k];
                val.w = emb[(size_t)(c0 + 4 * v + 3) * ED + k];
                *(float4*)&es[k * ESTR + 4 * v] = val;
            }
            if (t < 32) {
                float4 ev4 = *(const float4*)&enorm[c0 + 4 * t];
                *(float4*)&en_s[4 * t] = ev4;
            }
        }
        __syncthreads();

        float acc[4][8];
        #pragma unroll
        for (int i = 0; i < 4; i++)
            #pragma unroll
            for (int j = 0; j < 8; j++) acc[i][j] = 0.0f;

        #pragma unroll 8
        for (int k = 0; k < 64; k++) {
            float4 xv = *(const float4*)&zs[k * XSTR + 4 * rg];
            float4 e0 = *(const float4*)&es[k * ESTR + 8 * cg];
            float4 e1 = *(const float4*)&es[k * ESTR + 8 * cg + 4];
            float xa[4] = {xv.x, xv.y, xv.z, xv.w};
            float eb[8] = {e0.x, e0.y, e0.z, e0.w, e1.x, e1.y, e1.z, e1.w};
            #pragma unroll
            for (int i = 0; i < 4; i++)
                #pragma unroll
                for (int j = 0; j < 8; j++)
                    acc[i][j] = fmaf(xa[i], eb[j], acc[i][j]);
        }

        // epilogue: d = fl(fl(zn + en) - 2*dot); strict < keeps first index
        #pragma unroll
        for (int i = 0; i < 4; i++) {
            float zn = zn_s[4 * rg + i];
            #pragma unroll
            for (int j = 0; j < 8; j++) {
                int cl = 8 * cg + j;
                float A = zn + en_s[cl];
                float D = A - 2.0f * acc[i][j];
                if (D < bestd[i]) { bestd[i] = D; bestj[i] = c0 + cl; }
            }
        }
    }

    #pragma unroll
    for (int i = 0; i < 4; i++) {
        redd_s[cg * 64 + 4 * rg + i] = bestd[i];
        redj_s[cg * 64 + 4 * rg + i] = bestj[i];
    }
    __syncthreads();
    if (t < 64) {
        float bd = __builtin_huge_valf();
        int   bj = 0x7fffffff;
        #pragma unroll
        for (int c = 0; c < 16; c++) {
            float dd = redd_s[c * 64 + t];
            int   jj = redj_s[c * 64 + t];
            if (dd < bd || (dd == bd && jj < bj)) { bd = dd; bj = jj; }
        }
        int rowg = row0 + t;
        bj_s[t]       = bj;
        out_idx[rowg] = (float)bj;              // min_idx as float
        atomicExch(&out_samp[bj], 1.0f);        // scattered, low contention
    }
    __syncthreads();

    // Fused STE epilogue: z from zs (bit-exact), emb gather, SSE partial.
    // thread t: row r = t&63, k-range [16*kq, 16*kq+16)
    {
        int r  = t & 63;
        int kq = t >> 6;
        int bj = bj_s[r];
        const float* er = emb + (size_t)bj * ED + kq * 16;
        float sq = 0.0f;
        #pragma unroll
        for (int m = 0; m < 4; m++) {
            float4 ev = *(const float4*)&er[4 * m];
            float zv0 = zs[(kq * 16 + 4 * m + 0) * XSTR + r];
            float zv1 = zs[(kq * 16 + 4 * m + 1) * XSTR + r];
            float zv2 = zs[(kq * 16 + 4 * m + 2) * XSTR + r];
            float zv3 = zs[(kq * 16 + 4 * m + 3) * XSTR + r];
            float d0 = ev.x - zv0, d1 = ev.y - zv1, d2 = ev.z - zv2, d3 = ev.w - zv3;
            float4 o4;
            o4.x = zv0 + d0; o4.y = zv1 + d1; o4.z = zv2 + d2; o4.w = zv3 + d3;
            *(float4*)&out_zq[(size_t)(row0 + r) * ED + kq * 16 + 4 * m] = o4;
            sq += d0 * d0; sq += d1 * d1; sq += d2 * d2; sq += d3 * d3;
        }
        #pragma unroll
        for (int off = 32; off > 0; off >>= 1) sq += __shfl_down(sq, off, 64);
        int lane = t & 63, wv = t >> 6;
        if (lane == 0) warr[wv] = sq;
    }
    __syncthreads();
    if (t == 0)
        ssep[blockIdx.x] = (warr[0] + warr[1]) + (warr[2] + warr[3]);
}

// ---------------------------------------------------------------------------
// k_final: deterministic combine of 512 SSE partials (double tree) and the
// 16x64 contrastive partials; writes the loss scalar.
__global__ __launch_bounds__(256) void k_final(const float* __restrict__ ssep,
                                               const float* __restrict__ cpart,
                                               float* __restrict__ out_loss) {
    __shared__ double SD[256];
    __shared__ float  CS;
    int t = threadIdx.x;
    SD[t] = (double)ssep[t] + (double)ssep[t + 256];
    __syncthreads();
    #pragma unroll
    for (int off = 128; off > 0; off >>= 1) {
        if (t < off) SD[t] += SD[t + off];
        __syncthreads();
    }
    if (t < 64) {
        float v = 0.0f;
        #pragma unroll
        for (int m = 0; m < 16; m++) v += cpart[m * 64 + t];
        float sq = v * v;
        #pragma unroll
        for (int off = 32; off > 0; off >>= 1) sq += __shfl_down(sq, off, 64);
        if (t == 0) CS = sq / (1024.0f * 1024.0f);
    }
    __syncthreads();
    if (t == 0) {
        float m = (float)(SD[0] / (double)ZTOT);
        float loss = m + 0.25f * m;         // LEGACY: mse + BETA*mse
        out_loss[0] = loss + CS;
    }
}

// ---------------------------------------------------------------------------
extern "C" void kernel_launch(void* const* d_in, const int* in_sizes, int n_in,
                              void* d_out, int out_size, void* d_ws, size_t ws_size,
                              hipStream_t stream) {
    (void)in_sizes; (void)n_in; (void)out_size; (void)ws_size;
    const float* z_     = (const float*)d_in[0];
    const float* conv_w = (const float*)d_in[1];
    const float* conv_b = (const float*)d_in[2];
    const float* emb    = (const float*)d_in[3];

    float* out      = (float*)d_out;
    float* out_zq   = out;
    float* out_loss = out + OFF_LOSS;
    float* out_samp = out + OFF_SAMP;
    float* out_idx  = out + OFF_IDX;

    char*  ws       = (char*)d_ws;
    float* wz       = (float*)ws;                         // 2M floats (8 MB)
    float* enorm    = (float*)(ws + 8388608);             // 1024
    float* invn     = enorm + 1024;                       // 1024
    float* cpart    = (float*)(ws + 8396800);             // 16*64
    float* ssep     = (float*)(ws + 8400896);             // 512

    k_init    <<<132, 256, 0, stream>>>(out_samp, emb, enorm, invn);
    k_contrast<<<16,  256, 0, stream>>>(emb, invn, cpart);
    k_conv    <<<dim3(16, 32), 256, 0, stream>>>(z_, conv_w, conv_b, wz);
    k_dist    <<<512, 256, 0, stream>>>(wz, emb, enorm, out_idx, out_samp, out_zq, ssep);
    k_final   <<<1, 256, 0, stream>>>(ssep, cpart, out_loss);
}